// Round 6
// baseline (392.392 us; speedup 1.0000x reference)
//
#include <hip/hip_runtime.h>
#include <math.h>

#define NPIX 1024
#define NBOX 9216
#define ECAP 6144        // edge capacity (measured E ~ 500)
#define SFROW 36         // LDS tile row stride in dwords (144 B: 16B-aligned, not 0 mod 32)

typedef unsigned long long u64;

// ---------------- workspace layout (bytes) ----------------
#define O_H        4194304u     // 262144 f32 (hidden activations)
#define O_BOXES    5242880u     // 9216*4 f32
#define O_CONF     5390336u     // 9216 f32
#define O_KEYS     5427200u     // 9216 u64
#define O_RPART    5500928u     // 36*9216 i32
#define O_ORDER    6828032u     // 9216 i32
#define O_SBOX     6864896u     // 9216*4 f32 (boxes in sorted order)
#define O_SAREA    7012352u     // 9216 f32
#define O_VCNT     7049216u     // 1 i32 (Ecnt at +4)
#define O_ECNT     7049220u     // 1 i32
#define O_MASK     7049232u     // dead region: conv1 partials + edge buffer
#define O_KEEPW    17666064u    // 192 u64
#define O_EDGES    (O_MASK + 8388608u)   // 6144 u32, after partials

// ============ conv1: 3x3 SAME, 1280->256, fp32, double-buffered LDS ============
// grid (8 kc, 64 cog); 256 thr; thread owns 1x4 pixel strip x 4 co.
// LDS feat tile row stride 36 dwords -> <=2-way banks (free). 81408 B total
// -> exactly 2 blocks/CU.
__global__ __launch_bounds__(256) void conv1_kernel(const float* __restrict__ feat,
                                                    const float* __restrict__ w1,
                                                    float* __restrict__ partial,
                                                    int* __restrict__ counters) {
    const int kc  = blockIdx.x;          // 0..7
    const int cog = blockIdx.y;          // 0..63
    const int tid = threadIdx.x;
    const int x0 = (tid & 7) * 4;        // strip start col
    const int y  = tid >> 3;             // row 0..31
    const int ci0 = kc * 160;
    const int co0 = cog * 4;

    if (kc == 0 && cog == 0 && tid < 2) counters[tid] = 0;   // Vcnt, Ecnt

    __shared__ float sf[2][8 * 34 * SFROW];   // 2 x 39168 B
    __shared__ float sw[2][8 * 4 * 12];       // 2 x 1536 B

    // zero pad rows (row 0 and 33 per ci) in both buffers
    for (int e = tid; e < 8 * 2 * SFROW; e += 256) {
        int ci_l = e / (2 * SFROW), rem = e % (2 * SFROW);
        int r = rem / SFROW, c = rem % SFROW;
        sf[0][(ci_l * 34 + r * 33) * SFROW + c] = 0.f;
        sf[1][(ci_l * 34 + r * 33) * SFROW + c] = 0.f;
    }

    float acc[4][4];
#pragma unroll
    for (int a = 0; a < 4; ++a)
#pragma unroll
        for (int b = 0; b < 4; ++b) acc[a][b] = 0.f;

    // staging registers
    float4 st[8];
    float4 wst;
    const int wco = tid / 18, wf4 = tid % 18;   // weight-stager role (tid<72)

    // ---- prologue: stage chunk 0 into buf 0 ----
    {
        const float4* fg = (const float4*)(feat + (size_t)ci0 * NPIX);
#pragma unroll
        for (int k = 0; k < 8; ++k) st[k] = fg[(size_t)(tid + k * 256)];
        if (tid < 72)
            wst = *(const float4*)(w1 + (size_t)(co0 + wco) * 11520 +
                                   (size_t)ci0 * 9 + wf4 * 4);
#pragma unroll
        for (int k = 0; k < 8; ++k) {
            int e = tid + k * 256;
            int ci_l = e >> 8, rem = e & 255;
            int row = rem >> 3, f4c = rem & 7;
            *(float4*)&sf[0][(ci_l * 34 + row + 1) * SFROW + f4c * 4] = st[k];
        }
        if (tid < 72) {
            float wvv[4] = {wst.x, wst.y, wst.z, wst.w};
#pragma unroll
            for (int q = 0; q < 4; ++q) {
                int idx = wf4 * 4 + q;
                int cil = idx / 9, t = idx - cil * 9;
                sw[0][cil * 48 + wco * 12 + t] = wvv[q];
            }
        }
    }
    __syncthreads();

    for (int chunk = 0; chunk < 20; ++chunk) {
        const int cur = chunk & 1;
        const bool more = (chunk < 19);
        // issue next chunk's global loads early (latency hides under compute)
        if (more) {
            const int cbase = ci0 + (chunk + 1) * 8;
            const float4* fg = (const float4*)(feat + (size_t)cbase * NPIX);
#pragma unroll
            for (int k = 0; k < 8; ++k) st[k] = fg[(size_t)(tid + k * 256)];
            if (tid < 72)
                wst = *(const float4*)(w1 + (size_t)(co0 + wco) * 11520 +
                                       (size_t)cbase * 9 + wf4 * 4);
        }

        // ---- compute on buf[cur] ----
#pragma unroll
        for (int cil = 0; cil < 8; ++cil) {
            float f[3][6];
            const float* base = &sf[cur][(cil * 34 + y) * SFROW];
#pragma unroll
            for (int dy = 0; dy < 3; ++dy) {
                const float* rp = base + dy * SFROW;
                float4 mid = *(const float4*)(rp + x0);
                float lft = rp[x0 == 0 ? 0 : x0 - 1];
                float rgt = rp[x0 == 28 ? 31 : x0 + 4];
                f[dy][0] = (x0 == 0) ? 0.f : lft;
                f[dy][1] = mid.x; f[dy][2] = mid.y; f[dy][3] = mid.z; f[dy][4] = mid.w;
                f[dy][5] = (x0 == 28) ? 0.f : rgt;
            }
#pragma unroll
            for (int co = 0; co < 4; ++co) {
                const float* wrow = &sw[cur][cil * 48 + co * 12];
                float4 w0 = *(const float4*)(wrow);
                float4 w4 = *(const float4*)(wrow + 4);
                float  w8 = wrow[8];
                float wv[9] = {w0.x, w0.y, w0.z, w0.w, w4.x, w4.y, w4.z, w4.w, w8};
#pragma unroll
                for (int dy = 0; dy < 3; ++dy)
#pragma unroll
                    for (int dx = 0; dx < 3; ++dx) {
                        float wgt = wv[dy * 3 + dx];
#pragma unroll
                        for (int px = 0; px < 4; ++px)
                            acc[co][px] = fmaf(f[dy][px + dx], wgt, acc[co][px]);
                    }
            }
        }

        // ---- write staged regs into the other buffer ----
        if (more) {
            const int nxt = cur ^ 1;
#pragma unroll
            for (int k = 0; k < 8; ++k) {
                int e = tid + k * 256;
                int ci_l = e >> 8, rem = e & 255;
                int row = rem >> 3, f4c = rem & 7;
                *(float4*)&sf[nxt][(ci_l * 34 + row + 1) * SFROW + f4c * 4] = st[k];
            }
            if (tid < 72) {
                float wvv[4] = {wst.x, wst.y, wst.z, wst.w};
#pragma unroll
                for (int q = 0; q < 4; ++q) {
                    int idx = wf4 * 4 + q;
                    int cil = idx / 9, t = idx - cil * 9;
                    sw[nxt][cil * 48 + wco * 12 + t] = wvv[q];
                }
            }
            __syncthreads();
        }
    }

    const int pix = y * 32 + x0;
#pragma unroll
    for (int co = 0; co < 4; ++co) {
        float4 v = {acc[co][0], acc[co][1], acc[co][2], acc[co][3]};
        *(float4*)&partial[((size_t)kc * 256 + co0 + co) * NPIX + pix] = v;
    }
}

// ============ reduce 8 partials + bias + leaky relu ============
__global__ __launch_bounds__(256) void conv1_reduce(const float* __restrict__ partial,
                                                    const float* __restrict__ b1,
                                                    float* __restrict__ h) {
    int i = blockIdx.x * 256 + threadIdx.x;
    float s = b1[i >> 10];
#pragma unroll
    for (int kc = 0; kc < 8; ++kc) s += partial[(size_t)kc * 262144 + i];
    h[i] = s > 0.f ? s : 0.01f * s;
}

// ============ conv2 (1x1) + sigmoid + box decode + sort keys ============
__global__ __launch_bounds__(256) void conv2_decode(const float* __restrict__ h,
                                                    const float* __restrict__ w2,
                                                    const float* __restrict__ b2,
                                                    const float* __restrict__ anchors,
                                                    float* __restrict__ boxes,
                                                    float* __restrict__ conf_arr,
                                                    u64* __restrict__ keys,
                                                    int* __restrict__ Vcnt) {
    int gid = blockIdx.x * 256 + threadIdx.x;   // 9216
    int a = gid >> 10, p = gid & 1023;
    const float* wc0 = w2 + (size_t)(a * 6 + 0) * 256;
    const float* wc2 = w2 + (size_t)(a * 6 + 2) * 256;
    const float* wc3 = w2 + (size_t)(a * 6 + 3) * 256;
    const float* wc4 = w2 + (size_t)(a * 6 + 4) * 256;
    const float* wc5 = w2 + (size_t)(a * 6 + 5) * 256;
    float s0 = b2[a * 6 + 0], s2 = b2[a * 6 + 2], s3 = b2[a * 6 + 3],
          s4 = b2[a * 6 + 4], s5 = b2[a * 6 + 5];
#pragma unroll 4
    for (int ci = 0; ci < 256; ++ci) {
        float hv = h[ci * NPIX + p];
        s0 = fmaf(hv, wc0[ci], s0);
        s2 = fmaf(hv, wc2[ci], s2);
        s3 = fmaf(hv, wc3[ci], s3);
        s4 = fmaf(hv, wc4[ci], s4);
        s5 = fmaf(hv, wc5[ci], s5);
    }
    float conf = 1.f / (1.f + expf(-s0));
    float x = (float)(p & 31), y = (float)(p >> 5);
    float cx = x + 0.5f, cy = y + 0.5f;
    float aw = anchors[a * 2 + 0], ah = anchors[a * 2 + 1];
    float pcx = cx + s2 * aw, pcy = cy + s3 * ah;
    float pw = aw * expf(s4), ph = ah * expf(s5);
    int idx = p * 9 + a;   // (y,x,a) flat order
    boxes[idx * 4 + 0] = pcx - pw / 2.f;
    boxes[idx * 4 + 1] = pcy - ph / 2.f;
    boxes[idx * 4 + 2] = pcx + pw / 2.f;
    boxes[idx * 4 + 3] = pcy + ph / 2.f;
    conf_arr[idx] = conf;
    bool valid = conf > 0.5f;
    float score = valid ? conf : -1.0f;
    unsigned int sb = __float_as_uint(score);
    sb = (sb & 0x80000000u) ? ~sb : (sb | 0x80000000u);
    keys[idx] = ((u64)sb << 32) | (unsigned int)(~idx);
    if (valid) atomicAdd(Vcnt, 1);
}

// ============ rank (stable argsort) via pairwise count, j-split ============
__global__ __launch_bounds__(256) void rank_partial(const u64* __restrict__ keys,
                                                    int* __restrict__ rpart) {
    __shared__ u64 sk[256];
    int i = blockIdx.x * 256 + threadIdx.x;
    sk[threadIdx.x] = keys[blockIdx.y * 256 + threadIdx.x];
    __syncthreads();
    u64 ki = keys[i];
    int c = 0;
#pragma unroll 8
    for (int j = 0; j < 256; ++j) c += (sk[j] > ki) ? 1 : 0;
    rpart[blockIdx.y * NBOX + i] = c;
}

// rank_reduce + gather fused: the scattering thread knows (r, i)
__global__ __launch_bounds__(256) void rank_reduce(const int* __restrict__ rpart,
                                                   const float* __restrict__ boxes,
                                                   int* __restrict__ order,
                                                   float* __restrict__ sbox,
                                                   float* __restrict__ sarea) {
    int i = blockIdx.x * 256 + threadIdx.x;
    int r = 0;
    for (int b = 0; b < 36; ++b) r += rpart[b * NBOX + i];
    order[r] = i;
    float4 bv = ((const float4*)boxes)[i];
    ((float4*)sbox)[r] = bv;
    sarea[r] = fmaxf(bv.z - bv.x, 0.f) * fmaxf(bv.w - bv.y, 0.f);
}

// ============ sparse overlap edge list: (i,j), i<j<V, IoU>0.7 ============
__global__ __launch_bounds__(256) void nms_edges(const float* __restrict__ sbox,
                                                 const float* __restrict__ sarea,
                                                 const int* __restrict__ Vp,
                                                 unsigned* __restrict__ edges,
                                                 int* __restrict__ Ecnt) {
    int i = blockIdx.x;
    int V = *Vp;
    if (i >= V) return;
    float x1i = sbox[i * 4 + 0], y1i = sbox[i * 4 + 1];
    float x2i = sbox[i * 4 + 2], y2i = sbox[i * 4 + 3];
    float ai = sarea[i];
    int lane = threadIdx.x & 63;
    for (int j = i + 1 + threadIdx.x; ; j += 256) {
        bool active = (j < V);
        if (__ballot(active) == 0ull) break;
        bool hit = false;
        if (active) {
            float x1j = sbox[j * 4 + 0], y1j = sbox[j * 4 + 1];
            float x2j = sbox[j * 4 + 2], y2j = sbox[j * 4 + 3];
            float iw = fmaxf(fminf(x2i, x2j) - fmaxf(x1i, x1j), 0.f);
            float ih = fmaxf(fminf(y2i, y2j) - fmaxf(y1i, y1j), 0.f);
            float inter = iw * ih;
            float iou = inter / (ai + sarea[j] - inter + 1e-8f);
            hit = iou > 0.7f;
        }
        u64 bal = __ballot(hit);
        if (bal) {
            int cnt = __popcll(bal);
            unsigned base = 0;
            if (lane == 0) base = (unsigned)atomicAdd(Ecnt, cnt);
            base = (unsigned)__shfl((int)base, 0, 64);
            if (hit) {
                int pos = (int)base + __popcll(bal & ((1ull << lane) - 1ull));
                if (pos < ECAP) edges[pos] = ((unsigned)j << 16) | (unsigned)i;
            }
        }
    }
}

// ============ resolve: sort edges by target j, serial greedy apply ============
__global__ __launch_bounds__(256) void nms_resolve(const unsigned* __restrict__ edges,
                                                   const int* __restrict__ Ep,
                                                   const int* __restrict__ Vp,
                                                   u64* __restrict__ keepw) {
    __shared__ unsigned se[ECAP];
    __shared__ unsigned ss[ECAP];
    __shared__ u64 sup[144];
    const int tid = threadIdx.x;
    int E = *Ep; if (E > ECAP) E = ECAP;
    const int V = *Vp;
    for (int e = tid; e < E; e += 256) se[e] = edges[e];
    for (int w = tid; w < 144; w += 256) sup[w] = 0;
    __syncthreads();
    for (int e = tid; e < E; e += 256) {
        unsigned k = se[e];
        int r = 0;
        for (int q = 0; q < E; ++q) r += (se[q] < k) ? 1 : 0;
        ss[r] = k;
    }
    __syncthreads();
    if (tid == 0) {
        for (int e = 0; e < E; ++e) {
            unsigned k = ss[e];
            int i = (int)(k & 0xffffu), j = (int)(k >> 16);
            if (!((sup[i >> 6] >> (i & 63)) & 1ull))
                sup[j >> 6] |= 1ull << (j & 63);
        }
    }
    __syncthreads();
    for (int w = tid; w < 144; w += 256) {
        int base = w * 64;
        u64 vm;
        if (base + 64 <= V) vm = ~0ull;
        else if (base >= V) vm = 0ull;
        else vm = (1ull << (V - base)) - 1ull;
        keepw[w] = ~sup[w] & vm;
    }
}

// ============ final output write (all 9216 x 5) ============
__global__ __launch_bounds__(256) void finalize(const int* __restrict__ order,
                                                const int* __restrict__ Vp,
                                                const u64* __restrict__ keepw,
                                                const float* __restrict__ boxes,
                                                const float* __restrict__ conf_arr,
                                                float* __restrict__ out) {
    int p = blockIdx.x * 256 + threadIdx.x;   // sorted position
    int V = *Vp;
    int o = order[p];
    bool keep = false;
    if (p < V) keep = (keepw[p >> 6] >> (p & 63)) & 1ull;
    float k = keep ? 1.f : 0.f;
    out[o * 5 + 0] = boxes[o * 4 + 0] * k;
    out[o * 5 + 1] = boxes[o * 4 + 1] * k;
    out[o * 5 + 2] = boxes[o * 4 + 2] * k;
    out[o * 5 + 3] = boxes[o * 4 + 3] * k;
    out[o * 5 + 4] = conf_arr[o] * k;
}

extern "C" void kernel_launch(void* const* d_in, const int* in_sizes, int n_in,
                              void* d_out, int out_size, void* d_ws, size_t ws_size,
                              hipStream_t stream) {
    const float* feat    = (const float*)d_in[0];
    const float* anchors = (const float*)d_in[1];
    const float* w1      = (const float*)d_in[2];
    const float* b1      = (const float*)d_in[3];
    const float* w2      = (const float*)d_in[4];
    const float* b2      = (const float*)d_in[5];
    float* out = (float*)d_out;

    char* ws = (char*)d_ws;
    float* h       = (float*)(ws + O_H);
    float* boxes   = (float*)(ws + O_BOXES);
    float* conf    = (float*)(ws + O_CONF);
    u64*   keys    = (u64*)(ws + O_KEYS);
    int* rpart     = (int*)(ws + O_RPART);
    int* order     = (int*)(ws + O_ORDER);
    float* sbox    = (float*)(ws + O_SBOX);
    float* sarea   = (float*)(ws + O_SAREA);
    int* Vcnt      = (int*)(ws + O_VCNT);
    int* Ecnt      = (int*)(ws + O_ECNT);
    u64* keepw     = (u64*)(ws + O_KEEPW);
    float* partial = (float*)(ws + O_MASK);
    unsigned* edges = (unsigned*)(ws + O_EDGES);

    conv1_kernel<<<dim3(8, 64), 256, 0, stream>>>(feat, w1, partial, Vcnt);
    conv1_reduce<<<1024, 256, 0, stream>>>(partial, b1, h);
    conv2_decode<<<36, 256, 0, stream>>>(h, w2, b2, anchors, boxes, conf, keys, Vcnt);
    rank_partial<<<dim3(36, 36), 256, 0, stream>>>(keys, rpart);
    rank_reduce<<<36, 256, 0, stream>>>(rpart, boxes, order, sbox, sarea);
    nms_edges<<<NBOX, 256, 0, stream>>>(sbox, sarea, Vcnt, edges, Ecnt);
    nms_resolve<<<1, 256, 0, stream>>>(edges, Ecnt, Vcnt, keepw);
    finalize<<<36, 256, 0, stream>>>(order, Vcnt, keepw, boxes, conf, out);
}

// Round 7
// 270.930 us; speedup vs baseline: 1.4483x; 1.4483x over previous
//
#include <hip/hip_runtime.h>
#include <math.h>

#define NPIX 1024
#define NBOX 9216
#define ECAP 6144        // edge capacity (measured E ~ 500)

typedef unsigned long long u64;

// ---------------- workspace layout (bytes) ----------------
#define O_H        4194304u     // 262144 f32 (hidden activations)
#define O_BOXES    5242880u     // 9216*4 f32
#define O_CONF     5390336u     // 9216 f32
#define O_KEYS     5427200u     // 9216 u64
#define O_RPART    5500928u     // 36*9216 i32
#define O_ORDER    6828032u     // 9216 i32
#define O_SBOX     6864896u     // 9216*4 f32 (boxes in sorted order)
#define O_SAREA    7012352u     // 9216 f32
#define O_VCNT     7049216u     // 1 i32 (Ecnt at +4)
#define O_ECNT     7049220u     // 1 i32
#define O_MASK     7049232u     // dead region: conv1 partials + edge buffer
#define O_KEEPW    17666064u    // 192 u64
#define O_EDGES    (O_MASK + 8388608u)   // 6144 u32, after partials

// async global->LDS, 16B per lane; LDS dest = wave-uniform base + lane*16
__device__ inline void gll16(const void* g, void* l) {
    __builtin_amdgcn_global_load_lds(
        (const __attribute__((address_space(1))) unsigned int*)g,
        (__attribute__((address_space(3))) unsigned int*)l, 16, 0, 0);
}

// ============ conv1: 3x3 SAME, 1280->256, fp32 ============
// grid (8 kc, 64 cog); 256 thr; thread owns 1x4 pixel strip x 4 co.
// Double-buffered LDS feat tile (stride 32, bank-balanced), filled by
// global_load_lds (no staging VGPRs). Weights via wave-uniform scalar loads
// (K$, lgkmcnt) -- no weight LDS, single barrier per chunk, so the chunk+1
// DMA overlaps chunk-k compute.
__global__ __launch_bounds__(256) void conv1_kernel(const float* __restrict__ feat,
                                                    const float* __restrict__ w1,
                                                    float* __restrict__ partial,
                                                    int* __restrict__ counters) {
    const int kc  = blockIdx.x;          // 0..7
    const int cog = blockIdx.y;          // 0..63
    const int tid = threadIdx.x;
    const int x0 = (tid & 7) * 4;        // strip start col
    const int y  = tid >> 3;             // row 0..31
    const int ci0 = kc * 160;
    const int co0 = cog * 4;
    const int w   = tid >> 6;            // wave id 0..3

    if (kc == 0 && cog == 0 && tid < 2) counters[tid] = 0;   // Vcnt, Ecnt

    __shared__ float sf[2][8 * 34 * 32];   // 2 x 34816 B

    // zero the pad rows (rows 0 and 33 per ci) in both buffers
    for (int e = tid; e < 2 * 8 * 2 * 32; e += 256) {
        int b = e >> 9, rem = e & 511;
        int ci_l = rem >> 6, r = (rem >> 5) & 1, c = rem & 31;
        sf[b][(ci_l * 34 + r * 33) * 32 + c] = 0.f;
    }

    float acc[4][4];
#pragma unroll
    for (int a = 0; a < 4; ++a)
#pragma unroll
        for (int b = 0; b < 4; ++b) acc[a][b] = 0.f;

    // prologue: issue chunk 0 DMA into buf 0
    {
        const char* gbase = (const char*)(feat + (size_t)ci0 * NPIX) + (size_t)tid * 16;
#pragma unroll
        for (int j = 0; j < 8; ++j)
            gll16(gbase + (size_t)j * 4096, &sf[0][(j * 34 + 8 * w + 1) * 32]);
    }

    for (int chunk = 0; chunk < 20; ++chunk) {
        const int cur = chunk & 1;
        __syncthreads();   // drains vmcnt: buf[cur] DMA complete; pads visible

        // issue next chunk's DMA into the other buffer (flies during compute)
        if (chunk < 19) {
            const int nxt = cur ^ 1;
            const char* gbase = (const char*)(feat + (size_t)(ci0 + (chunk + 1) * 8) * NPIX)
                                + (size_t)tid * 16;
#pragma unroll
            for (int j = 0; j < 8; ++j)
                gll16(gbase + (size_t)j * 4096, &sf[nxt][(j * 34 + 8 * w + 1) * 32]);
        }

        const int cbase = ci0 + chunk * 8;
#pragma unroll
        for (int cil = 0; cil < 8; ++cil) {
            float f[3][6];
            const float* base = &sf[cur][(cil * 34 + y) * 32];
#pragma unroll
            for (int dy = 0; dy < 3; ++dy) {
                const float* rp = base + dy * 32;
                float4 mid = *(const float4*)(rp + x0);
                float lft = rp[x0 == 0 ? 0 : x0 - 1];
                float rgt = rp[x0 == 28 ? 31 : x0 + 4];
                f[dy][0] = (x0 == 0) ? 0.f : lft;
                f[dy][1] = mid.x; f[dy][2] = mid.y; f[dy][3] = mid.z; f[dy][4] = mid.w;
                f[dy][5] = (x0 == 28) ? 0.f : rgt;
            }
#pragma unroll
            for (int co = 0; co < 4; ++co) {
                // wave-uniform address -> scalar loads through K$
                const float* wp = w1 + (size_t)(co0 + co) * 11520 + (size_t)(cbase + cil) * 9;
                float wv[9];
#pragma unroll
                for (int t = 0; t < 9; ++t) wv[t] = wp[t];
#pragma unroll
                for (int dy = 0; dy < 3; ++dy)
#pragma unroll
                    for (int dx = 0; dx < 3; ++dx) {
                        float wgt = wv[dy * 3 + dx];
#pragma unroll
                        for (int px = 0; px < 4; ++px)
                            acc[co][px] = fmaf(f[dy][px + dx], wgt, acc[co][px]);
                    }
            }
        }
    }

    const int pix = y * 32 + x0;
#pragma unroll
    for (int co = 0; co < 4; ++co) {
        float4 v = {acc[co][0], acc[co][1], acc[co][2], acc[co][3]};
        *(float4*)&partial[((size_t)kc * 256 + co0 + co) * NPIX + pix] = v;
    }
}

// ============ reduce 8 partials + bias + leaky relu ============
__global__ __launch_bounds__(256) void conv1_reduce(const float* __restrict__ partial,
                                                    const float* __restrict__ b1,
                                                    float* __restrict__ h) {
    int i = blockIdx.x * 256 + threadIdx.x;
    float s = b1[i >> 10];
#pragma unroll
    for (int kc = 0; kc < 8; ++kc) s += partial[(size_t)kc * 262144 + i];
    h[i] = s > 0.f ? s : 0.01f * s;
}

// ============ conv2 (1x1) + sigmoid + box decode + sort keys ============
__global__ __launch_bounds__(256) void conv2_decode(const float* __restrict__ h,
                                                    const float* __restrict__ w2,
                                                    const float* __restrict__ b2,
                                                    const float* __restrict__ anchors,
                                                    float* __restrict__ boxes,
                                                    float* __restrict__ conf_arr,
                                                    u64* __restrict__ keys,
                                                    int* __restrict__ Vcnt) {
    int gid = blockIdx.x * 256 + threadIdx.x;   // 9216
    int a = gid >> 10, p = gid & 1023;
    const float* wc0 = w2 + (size_t)(a * 6 + 0) * 256;
    const float* wc2 = w2 + (size_t)(a * 6 + 2) * 256;
    const float* wc3 = w2 + (size_t)(a * 6 + 3) * 256;
    const float* wc4 = w2 + (size_t)(a * 6 + 4) * 256;
    const float* wc5 = w2 + (size_t)(a * 6 + 5) * 256;
    float s0 = b2[a * 6 + 0], s2 = b2[a * 6 + 2], s3 = b2[a * 6 + 3],
          s4 = b2[a * 6 + 4], s5 = b2[a * 6 + 5];
#pragma unroll 4
    for (int ci = 0; ci < 256; ++ci) {
        float hv = h[ci * NPIX + p];
        s0 = fmaf(hv, wc0[ci], s0);
        s2 = fmaf(hv, wc2[ci], s2);
        s3 = fmaf(hv, wc3[ci], s3);
        s4 = fmaf(hv, wc4[ci], s4);
        s5 = fmaf(hv, wc5[ci], s5);
    }
    float conf = 1.f / (1.f + expf(-s0));
    float x = (float)(p & 31), y = (float)(p >> 5);
    float cx = x + 0.5f, cy = y + 0.5f;
    float aw = anchors[a * 2 + 0], ah = anchors[a * 2 + 1];
    float pcx = cx + s2 * aw, pcy = cy + s3 * ah;
    float pw = aw * expf(s4), ph = ah * expf(s5);
    int idx = p * 9 + a;   // (y,x,a) flat order
    boxes[idx * 4 + 0] = pcx - pw / 2.f;
    boxes[idx * 4 + 1] = pcy - ph / 2.f;
    boxes[idx * 4 + 2] = pcx + pw / 2.f;
    boxes[idx * 4 + 3] = pcy + ph / 2.f;
    conf_arr[idx] = conf;
    bool valid = conf > 0.5f;
    float score = valid ? conf : -1.0f;
    unsigned int sb = __float_as_uint(score);
    sb = (sb & 0x80000000u) ? ~sb : (sb | 0x80000000u);
    keys[idx] = ((u64)sb << 32) | (unsigned int)(~idx);
    if (valid) atomicAdd(Vcnt, 1);
}

// ============ rank (stable argsort) via pairwise count, j-split ============
__global__ __launch_bounds__(256) void rank_partial(const u64* __restrict__ keys,
                                                    int* __restrict__ rpart) {
    __shared__ u64 sk[256];
    int i = blockIdx.x * 256 + threadIdx.x;
    sk[threadIdx.x] = keys[blockIdx.y * 256 + threadIdx.x];
    __syncthreads();
    u64 ki = keys[i];
    int c = 0;
#pragma unroll 8
    for (int j = 0; j < 256; ++j) c += (sk[j] > ki) ? 1 : 0;
    rpart[blockIdx.y * NBOX + i] = c;
}

// rank_reduce + gather fused: the scattering thread knows (r, i)
__global__ __launch_bounds__(256) void rank_reduce(const int* __restrict__ rpart,
                                                   const float* __restrict__ boxes,
                                                   int* __restrict__ order,
                                                   float* __restrict__ sbox,
                                                   float* __restrict__ sarea) {
    int i = blockIdx.x * 256 + threadIdx.x;
    int r = 0;
    for (int b = 0; b < 36; ++b) r += rpart[b * NBOX + i];
    order[r] = i;
    float4 bv = ((const float4*)boxes)[i];
    ((float4*)sbox)[r] = bv;
    sarea[r] = fmaxf(bv.z - bv.x, 0.f) * fmaxf(bv.w - bv.y, 0.f);
}

// ============ sparse overlap edge list: (i,j), i<j<V, IoU>0.7 ============
__global__ __launch_bounds__(256) void nms_edges(const float* __restrict__ sbox,
                                                 const float* __restrict__ sarea,
                                                 const int* __restrict__ Vp,
                                                 unsigned* __restrict__ edges,
                                                 int* __restrict__ Ecnt) {
    int i = blockIdx.x;
    int V = *Vp;
    if (i >= V) return;
    float x1i = sbox[i * 4 + 0], y1i = sbox[i * 4 + 1];
    float x2i = sbox[i * 4 + 2], y2i = sbox[i * 4 + 3];
    float ai = sarea[i];
    int lane = threadIdx.x & 63;
    for (int j = i + 1 + threadIdx.x; ; j += 256) {
        bool active = (j < V);
        if (__ballot(active) == 0ull) break;
        bool hit = false;
        if (active) {
            float x1j = sbox[j * 4 + 0], y1j = sbox[j * 4 + 1];
            float x2j = sbox[j * 4 + 2], y2j = sbox[j * 4 + 3];
            float iw = fmaxf(fminf(x2i, x2j) - fmaxf(x1i, x1j), 0.f);
            float ih = fmaxf(fminf(y2i, y2j) - fmaxf(y1i, y1j), 0.f);
            float inter = iw * ih;
            float iou = inter / (ai + sarea[j] - inter + 1e-8f);
            hit = iou > 0.7f;
        }
        u64 bal = __ballot(hit);
        if (bal) {
            int cnt = __popcll(bal);
            unsigned base = 0;
            if (lane == 0) base = (unsigned)atomicAdd(Ecnt, cnt);
            base = (unsigned)__shfl((int)base, 0, 64);
            if (hit) {
                int pos = (int)base + __popcll(bal & ((1ull << lane) - 1ull));
                if (pos < ECAP) edges[pos] = ((unsigned)j << 16) | (unsigned)i;
            }
        }
    }
}

// ============ resolve: sort edges by target j, serial greedy apply ============
__global__ __launch_bounds__(256) void nms_resolve(const unsigned* __restrict__ edges,
                                                   const int* __restrict__ Ep,
                                                   const int* __restrict__ Vp,
                                                   u64* __restrict__ keepw) {
    __shared__ unsigned se[ECAP];
    __shared__ unsigned ss[ECAP];
    __shared__ u64 sup[144];
    const int tid = threadIdx.x;
    int E = *Ep; if (E > ECAP) E = ECAP;
    const int V = *Vp;
    for (int e = tid; e < E; e += 256) se[e] = edges[e];
    for (int w = tid; w < 144; w += 256) sup[w] = 0;
    __syncthreads();
    for (int e = tid; e < E; e += 256) {
        unsigned k = se[e];
        int r = 0;
        for (int q = 0; q < E; ++q) r += (se[q] < k) ? 1 : 0;
        ss[r] = k;
    }
    __syncthreads();
    if (tid == 0) {
        for (int e = 0; e < E; ++e) {
            unsigned k = ss[e];
            int i = (int)(k & 0xffffu), j = (int)(k >> 16);
            if (!((sup[i >> 6] >> (i & 63)) & 1ull))
                sup[j >> 6] |= 1ull << (j & 63);
        }
    }
    __syncthreads();
    for (int w = tid; w < 144; w += 256) {
        int base = w * 64;
        u64 vm;
        if (base + 64 <= V) vm = ~0ull;
        else if (base >= V) vm = 0ull;
        else vm = (1ull << (V - base)) - 1ull;
        keepw[w] = ~sup[w] & vm;
    }
}

// ============ final output write (all 9216 x 5) ============
__global__ __launch_bounds__(256) void finalize(const int* __restrict__ order,
                                                const int* __restrict__ Vp,
                                                const u64* __restrict__ keepw,
                                                const float* __restrict__ boxes,
                                                const float* __restrict__ conf_arr,
                                                float* __restrict__ out) {
    int p = blockIdx.x * 256 + threadIdx.x;   // sorted position
    int V = *Vp;
    int o = order[p];
    bool keep = false;
    if (p < V) keep = (keepw[p >> 6] >> (p & 63)) & 1ull;
    float k = keep ? 1.f : 0.f;
    out[o * 5 + 0] = boxes[o * 4 + 0] * k;
    out[o * 5 + 1] = boxes[o * 4 + 1] * k;
    out[o * 5 + 2] = boxes[o * 4 + 2] * k;
    out[o * 5 + 3] = boxes[o * 4 + 3] * k;
    out[o * 5 + 4] = conf_arr[o] * k;
}

extern "C" void kernel_launch(void* const* d_in, const int* in_sizes, int n_in,
                              void* d_out, int out_size, void* d_ws, size_t ws_size,
                              hipStream_t stream) {
    const float* feat    = (const float*)d_in[0];
    const float* anchors = (const float*)d_in[1];
    const float* w1      = (const float*)d_in[2];
    const float* b1      = (const float*)d_in[3];
    const float* w2      = (const float*)d_in[4];
    const float* b2      = (const float*)d_in[5];
    float* out = (float*)d_out;

    char* ws = (char*)d_ws;
    float* h       = (float*)(ws + O_H);
    float* boxes   = (float*)(ws + O_BOXES);
    float* conf    = (float*)(ws + O_CONF);
    u64*   keys    = (u64*)(ws + O_KEYS);
    int* rpart     = (int*)(ws + O_RPART);
    int* order     = (int*)(ws + O_ORDER);
    float* sbox    = (float*)(ws + O_SBOX);
    float* sarea   = (float*)(ws + O_SAREA);
    int* Vcnt      = (int*)(ws + O_VCNT);
    int* Ecnt      = (int*)(ws + O_ECNT);
    u64* keepw     = (u64*)(ws + O_KEEPW);
    float* partial = (float*)(ws + O_MASK);
    unsigned* edges = (unsigned*)(ws + O_EDGES);

    conv1_kernel<<<dim3(8, 64), 256, 0, stream>>>(feat, w1, partial, Vcnt);
    conv1_reduce<<<1024, 256, 0, stream>>>(partial, b1, h);
    conv2_decode<<<36, 256, 0, stream>>>(h, w2, b2, anchors, boxes, conf, keys, Vcnt);
    rank_partial<<<dim3(36, 36), 256, 0, stream>>>(keys, rpart);
    rank_reduce<<<36, 256, 0, stream>>>(rpart, boxes, order, sbox, sarea);
    nms_edges<<<NBOX, 256, 0, stream>>>(sbox, sarea, Vcnt, edges, Ecnt);
    nms_resolve<<<1, 256, 0, stream>>>(edges, Ecnt, Vcnt, keepw);
    finalize<<<36, 256, 0, stream>>>(order, Vcnt, keepw, boxes, conf, out);
}